// Round 1
// baseline (618.363 us; speedup 1.0000x reference)
//
#include <hip/hip_runtime.h>
#include <math.h>

#define B_  8
#define L_  4096
#define T_  128
#define DH  1024
#define DG  256
#define DP  256

// Kernel 1: Qk[b,t,d] = scale * sum_p (sum_g G[b,t,g] Wq[g,p]) * Wk[d,p]
// Folds Wk and the 1/sqrt(DP) scale into Q so K is never materialized.
__global__ __launch_bounds__(256) void qk_kernel(const float* __restrict__ G,
                                                 const float* __restrict__ Wq,
                                                 const float* __restrict__ Wk,
                                                 float* __restrict__ Qk) {
    __shared__ float Gs[DG];
    __shared__ float Qs[DP];
    const int bt  = blockIdx.x;   // b*T + t, 0..1023
    const int tid = threadIdx.x;  // 256 threads

    Gs[tid] = G[(size_t)bt * DG + tid];
    __syncthreads();

    float q = 0.f;
    #pragma unroll 4
    for (int g = 0; g < DG; ++g) q += Gs[g] * Wq[(size_t)g * DP + tid];
    Qs[tid] = q;
    __syncthreads();

    #pragma unroll
    for (int dd = 0; dd < 4; ++dd) {
        const int d = dd * 256 + tid;
        float acc = 0.f;
        #pragma unroll 4
        for (int p = 0; p < DP; ++p) acc += Qs[p] * Wk[(size_t)d * DP + p];
        Qk[(size_t)bt * DH + d] = acc * 0.0625f;  // 1/sqrt(256)
    }
}

// Kernel 2: logits[b,t,l] = sum_d Qk[b,t,d] * H[b,l,d]   (64x64 tile, KT=16)
__global__ __launch_bounds__(256) void logits_kernel(const float* __restrict__ Qk,
                                                     const float* __restrict__ H,
                                                     float* __restrict__ logits) {
    __shared__ float As[16][68];  // [k][t]  pad->68: stores 2-way (free), 16B-aligned reads
    __shared__ float Bs[16][68];  // [k][l]
    const int b  = blockIdx.z;
    const int t0 = blockIdx.y * 64;
    const int l0 = blockIdx.x * 64;
    const int tid = threadIdx.x;
    const int jj = tid & 15, ii = tid >> 4;   // load coords
    const int tr = tid >> 4, tc = tid & 15;   // compute coords (4x4 micro-tile)

    const float* Ab = Qk + ((size_t)b * T_ + t0) * DH;
    const float* Bb = H  + ((size_t)b * L_ + l0) * DH;

    float acc[4][4] = {};
    for (int k0 = 0; k0 < DH; k0 += 16) {
        #pragma unroll
        for (int s = 0; s < 4; ++s) {
            As[jj][ii + s * 16] = Ab[(size_t)(ii + s * 16) * DH + k0 + jj];
            Bs[jj][ii + s * 16] = Bb[(size_t)(ii + s * 16) * DH + k0 + jj];
        }
        __syncthreads();
        #pragma unroll
        for (int k = 0; k < 16; ++k) {
            const float a0 = As[k][tr * 4 + 0], a1 = As[k][tr * 4 + 1];
            const float a2 = As[k][tr * 4 + 2], a3 = As[k][tr * 4 + 3];
            const float b0 = Bs[k][tc * 4 + 0], b1 = Bs[k][tc * 4 + 1];
            const float b2 = Bs[k][tc * 4 + 2], b3 = Bs[k][tc * 4 + 3];
            acc[0][0] += a0 * b0; acc[0][1] += a0 * b1; acc[0][2] += a0 * b2; acc[0][3] += a0 * b3;
            acc[1][0] += a1 * b0; acc[1][1] += a1 * b1; acc[1][2] += a1 * b2; acc[1][3] += a1 * b3;
            acc[2][0] += a2 * b0; acc[2][1] += a2 * b1; acc[2][2] += a2 * b2; acc[2][3] += a2 * b3;
            acc[3][0] += a3 * b0; acc[3][1] += a3 * b1; acc[3][2] += a3 * b2; acc[3][3] += a3 * b3;
        }
        __syncthreads();
    }
    #pragma unroll
    for (int i = 0; i < 4; ++i)
        #pragma unroll
        for (int j = 0; j < 4; ++j)
            logits[((size_t)b * T_ + t0 + tr * 4 + i) * L_ + l0 + tc * 4 + j] = acc[i][j];
}

// Kernel 3: masked row softmax over L (in-place on logits -> alpha)
__global__ __launch_bounds__(256) void softmax_kernel(float* __restrict__ logits,
                                                      const int* __restrict__ mask) {
    const int row = blockIdx.x;       // b*T + t
    const int b   = row >> 7;         // row / 128
    const int tid = threadIdx.x;
    float* ptr = logits + (size_t)row * L_;
    const int* mrow = mask + (size_t)b * L_;

    float vals[16];
    float vmax = -3.0e38f;
    #pragma unroll
    for (int s = 0; s < 16; ++s) {
        const int l = tid + s * 256;
        float v = ptr[l];
        v = mrow[l] ? -3.0e38f : v;   // 1 = masked out
        vals[s] = v;
        vmax = fmaxf(vmax, v);
    }
    #pragma unroll
    for (int off = 32; off; off >>= 1) vmax = fmaxf(vmax, __shfl_down(vmax, off, 64));

    __shared__ float red[4];
    __shared__ float bcast;
    const int wid = tid >> 6, lane = tid & 63;
    if (lane == 0) red[wid] = vmax;
    __syncthreads();
    if (tid == 0) bcast = fmaxf(fmaxf(red[0], red[1]), fmaxf(red[2], red[3]));
    __syncthreads();
    const float m = bcast;

    float sum = 0.f;
    #pragma unroll
    for (int s = 0; s < 16; ++s) {
        vals[s] = __expf(vals[s] - m);   // masked: exp(-3e38 - m) == 0
        sum += vals[s];
    }
    #pragma unroll
    for (int off = 32; off; off >>= 1) sum += __shfl_down(sum, off, 64);
    __syncthreads();
    if (lane == 0) red[wid] = sum;
    __syncthreads();
    if (tid == 0) bcast = red[0] + red[1] + red[2] + red[3];
    __syncthreads();
    const float inv = 1.0f / bcast;

    #pragma unroll
    for (int s = 0; s < 16; ++s) ptr[tid + s * 256] = vals[s] * inv;
}

// Kernel 4: Z[b,t,d] = sum_l alpha[b,t,l] * H[b,l,d]   (32x64 tile, KT=32)
__global__ __launch_bounds__(256) void z_kernel(const float* __restrict__ alpha,
                                                const float* __restrict__ H,
                                                float* __restrict__ Z) {
    __shared__ float As[32][33];  // [l][t]
    __shared__ float Bs[32][68];  // [l][d]
    const int b  = blockIdx.z;
    const int t0 = blockIdx.y * 32;
    const int d0 = blockIdx.x * 64;
    const int tid = threadIdx.x;
    const int tr = tid >> 4, tc = tid & 15;  // 2x4 micro-tile

    const float* Ab = alpha + ((size_t)b * T_ + t0) * L_;
    const float* Hb = H + (size_t)b * L_ * DH;

    float acc[2][4] = {};
    for (int k0 = 0; k0 < L_; k0 += 32) {
        const int j  = tid & 31, i0 = tid >> 5;  // A loads: 32 cols x 8 rows/iter
        #pragma unroll
        for (int s = 0; s < 4; ++s)
            As[j][i0 + s * 8] = Ab[(size_t)(i0 + s * 8) * L_ + k0 + j];
        const int n  = tid & 63, kk = tid >> 6;  // B loads: 64 cols x 4 rows/iter
        #pragma unroll
        for (int s = 0; s < 8; ++s)
            Bs[kk + s * 4][n] = Hb[(size_t)(k0 + kk + s * 4) * DH + d0 + n];
        __syncthreads();
        #pragma unroll
        for (int k = 0; k < 32; ++k) {
            const float a0 = As[k][tr * 2 + 0], a1 = As[k][tr * 2 + 1];
            const float b0 = Bs[k][tc * 4 + 0], b1 = Bs[k][tc * 4 + 1];
            const float b2 = Bs[k][tc * 4 + 2], b3 = Bs[k][tc * 4 + 3];
            acc[0][0] += a0 * b0; acc[0][1] += a0 * b1; acc[0][2] += a0 * b2; acc[0][3] += a0 * b3;
            acc[1][0] += a1 * b0; acc[1][1] += a1 * b1; acc[1][2] += a1 * b2; acc[1][3] += a1 * b3;
        }
        __syncthreads();
    }
    #pragma unroll
    for (int i = 0; i < 2; ++i)
        #pragma unroll
        for (int j = 0; j < 4; ++j)
            Z[((size_t)b * T_ + t0 + tr * 2 + i) * DH + d0 + tc * 4 + j] = acc[i][j];
}

extern "C" void kernel_launch(void* const* d_in, const int* in_sizes, int n_in,
                              void* d_out, int out_size, void* d_ws, size_t ws_size,
                              hipStream_t stream) {
    const float* H    = (const float*)d_in[0];   // [8, 4096, 1024]
    const float* G    = (const float*)d_in[1];   // [8, 128, 256]
    const int*   mask = (const int*)d_in[2];     // [8, 4096], 1 = masked out
    const float* Wk   = (const float*)d_in[3];   // [1024, 256]
    const float* Wq   = (const float*)d_in[4];   // [256, 256]
    float* Z = (float*)d_out;                    // [8, 128, 1024]

    float* qk     = (float*)d_ws;                   // 8*128*1024 floats = 4 MB
    float* logits = qk + (size_t)B_ * T_ * DH;      // 8*128*4096 floats = 16 MB

    qk_kernel<<<B_ * T_, 256, 0, stream>>>(G, Wq, Wk, qk);
    logits_kernel<<<dim3(L_ / 64, T_ / 64, B_), 256, 0, stream>>>(qk, H, logits);
    softmax_kernel<<<B_ * T_, 256, 0, stream>>>(logits, mask);
    z_kernel<<<dim3(DH / 64, T_ / 32, B_), 256, 0, stream>>>(logits, H, Z);
}

// Round 2
// 337.547 us; speedup vs baseline: 1.8319x; 1.8319x over previous
//
#include <hip/hip_runtime.h>
#include <hip/hip_bf16.h>
#include <math.h>

#define B_  8
#define L_  4096
#define T_  128
#define DH  1024
#define DG  256
#define DP  256
#define BK  64

typedef short bf16x8 __attribute__((ext_vector_type(8)));
typedef float f32x4  __attribute__((ext_vector_type(4)));

#define AS1(p) ((const __attribute__((address_space(1))) void*)(p))
#define AS3(p) ((__attribute__((address_space(3))) void*)(p))

__device__ __forceinline__ unsigned short f2bf(float f) {
    unsigned u = __float_as_uint(f);
    unsigned r = (u + 0x7FFFu + ((u >> 16) & 1u)) >> 16;  // RNE
    return (unsigned short)r;
}

// ---------------- Kernel 1: Qk[b,t,d] = (1/16) * sum_p (G.Wq)[t,p] * Wk[d,p], bf16 out
__global__ __launch_bounds__(256) void qk_kernel(const float* __restrict__ G,
                                                 const float* __restrict__ Wq,
                                                 const float* __restrict__ Wk,
                                                 unsigned short* __restrict__ Qk) {
    __shared__ float Gs[DG];
    __shared__ float Qs[DP];
    const int bt  = blockIdx.x;
    const int tid = threadIdx.x;

    Gs[tid] = G[(size_t)bt * DG + tid];
    __syncthreads();
    float q = 0.f;
    #pragma unroll 4
    for (int g = 0; g < DG; ++g) q += Gs[g] * Wq[(size_t)g * DP + tid];
    Qs[tid] = q * 0.0625f;  // fold 1/sqrt(256)
    __syncthreads();

    // 16 lanes cooperate per output d (coalesced-ish Wk reads + shuffle reduce)
    const int t = tid & 15, dsub = tid >> 4;
    for (int pass = 0; pass < 64; ++pass) {
        const int d = pass * 16 + dsub;
        const float* w = Wk + (size_t)d * DP + t * 16;
        float s = 0.f;
        #pragma unroll
        for (int i = 0; i < 16; ++i) s += Qs[t * 16 + i] * w[i];
        s += __shfl_down(s, 8, 64);
        s += __shfl_down(s, 4, 64);
        s += __shfl_down(s, 2, 64);
        s += __shfl_down(s, 1, 64);
        if (t == 0) Qk[(size_t)bt * DH + d] = f2bf(s);
    }
}

// ---------------- Kernel 2: logits = Qk(bf16) . H^T(fp32->bf16)   tile 128t x 64l, BK=64
__global__ __launch_bounds__(256) void logits_kernel(const unsigned short* __restrict__ Qk,
                                                     const float* __restrict__ H,
                                                     float* __restrict__ logits) {
    __shared__ __attribute__((aligned(16))) unsigned short As[T_ * BK];   // [t][k], 128B rows
    __shared__ __attribute__((aligned(16))) unsigned short Bs[64 * BK];   // [l][k], 128B rows
    const int b = blockIdx.y, l0 = blockIdx.x * 64;
    const int tid = threadIdx.x, wave = tid >> 6, lane = tid & 63;
    const unsigned short* Ab = Qk + (size_t)b * T_ * DH;
    const float*          Hb = H + ((size_t)b * L_ + l0) * DH;

    const int lm = lane & 15, quad = lane >> 4;
    const int wm = wave >> 1, wn = wave & 1;
    f32x4 acc[4][2] = {};

    const int ar = lane >> 3, akb = (lane & 7) * 8;       // A stage coords
    const int bc = (tid & 15) * 4, br0 = tid >> 4;        // B stage coords

    for (int k0 = 0; k0 < DH; k0 += BK) {
        // A: async global->LDS, 128 rows x 64 bf16 (4 waves x 4 issues x 1KB)
        #pragma unroll
        for (int s = 0; s < 4; ++s) {
            const int rowb = s * 32 + wave * 8;
            const unsigned short* gp = Ab + (size_t)(rowb + ar) * DH + k0 + akb;
            __builtin_amdgcn_global_load_lds(AS1(gp), AS3(&As[rowb * BK]), 16, 0, 0);
        }
        // B: 64 rows x 64 k fp32 -> bf16 LDS (16 lanes cover one 256B row)
        #pragma unroll
        for (int s = 0; s < 4; ++s) {
            const int row = br0 + s * 16;
            const float4 v = *(const float4*)(Hb + (size_t)row * DH + k0 + bc);
            ushort4 p;
            p.x = f2bf(v.x); p.y = f2bf(v.y); p.z = f2bf(v.z); p.w = f2bf(v.w);
            *(ushort4*)(&Bs[row * BK + bc]) = p;
        }
        __syncthreads();
        #pragma unroll
        for (int ks = 0; ks < 2; ++ks) {
            bf16x8 a[4], bf[2];
            #pragma unroll
            for (int i = 0; i < 4; ++i)
                a[i] = *(const bf16x8*)(&As[(wm * 64 + i * 16 + lm) * BK + ks * 32 + quad * 8]);
            #pragma unroll
            for (int j = 0; j < 2; ++j)
                bf[j] = *(const bf16x8*)(&Bs[(wn * 32 + j * 16 + lm) * BK + ks * 32 + quad * 8]);
            #pragma unroll
            for (int i = 0; i < 4; ++i)
                #pragma unroll
                for (int j = 0; j < 2; ++j)
                    acc[i][j] = __builtin_amdgcn_mfma_f32_16x16x32_bf16(a[i], bf[j], acc[i][j], 0, 0, 0);
        }
        __syncthreads();
    }
    float* Cb = logits + (size_t)b * T_ * L_ + l0;
    #pragma unroll
    for (int i = 0; i < 4; ++i)
        #pragma unroll
        for (int j = 0; j < 2; ++j)
            #pragma unroll
            for (int r = 0; r < 4; ++r)
                Cb[(size_t)(wm * 64 + i * 16 + quad * 4 + r) * L_ + wn * 32 + j * 16 + lm] = acc[i][j][r];
}

// ---------------- Kernel 3: masked softmax over L, fp32 in -> bf16 alpha out
__global__ __launch_bounds__(256) void softmax_kernel(const float* __restrict__ logits,
                                                      const int* __restrict__ mask,
                                                      unsigned short* __restrict__ alpha) {
    const int row = blockIdx.x;       // b*T + t
    const int b   = row >> 7;
    const int tid = threadIdx.x;
    const float* ptr = logits + (size_t)row * L_;
    const int* mrow = mask + (size_t)b * L_;

    float vals[16];
    float vmax = -3.0e38f;
    #pragma unroll
    for (int s = 0; s < 16; ++s) {
        const int l = tid + s * 256;
        float v = ptr[l];
        v = mrow[l] ? -3.0e38f : v;
        vals[s] = v;
        vmax = fmaxf(vmax, v);
    }
    #pragma unroll
    for (int off = 32; off; off >>= 1) vmax = fmaxf(vmax, __shfl_down(vmax, off, 64));

    __shared__ float red[4];
    __shared__ float bcast;
    const int wid = tid >> 6, lane = tid & 63;
    if (lane == 0) red[wid] = vmax;
    __syncthreads();
    if (tid == 0) bcast = fmaxf(fmaxf(red[0], red[1]), fmaxf(red[2], red[3]));
    __syncthreads();
    const float m = bcast;

    float sum = 0.f;
    #pragma unroll
    for (int s = 0; s < 16; ++s) {
        vals[s] = __expf(vals[s] - m);
        sum += vals[s];
    }
    #pragma unroll
    for (int off = 32; off; off >>= 1) sum += __shfl_down(sum, off, 64);
    __syncthreads();
    if (lane == 0) red[wid] = sum;
    __syncthreads();
    if (tid == 0) bcast = red[0] + red[1] + red[2] + red[3];
    __syncthreads();
    const float inv = 1.0f / bcast;

    unsigned short* arow = alpha + (size_t)row * L_;
    #pragma unroll
    for (int s = 0; s < 16; ++s) arow[tid + s * 256] = f2bf(vals[s] * inv);
}

// ---------------- Kernel 4: Z-partials = alpha(bf16) . H(fp32->bf16, LDS-transposed)
// tile 128t x 64d, K = L/4 per chunk; grid (16 d-tiles, 8 b, 4 chunks)
__global__ __launch_bounds__(256) void z_kernel(const unsigned short* __restrict__ alpha,
                                                const float* __restrict__ H,
                                                float* __restrict__ partials) {
    __shared__ __attribute__((aligned(16))) unsigned short As[T_ * BK];       // [t][l], 128B rows
    __shared__ __attribute__((aligned(16))) unsigned short Bs[64 * (BK + 2)]; // [d][l], stride 66
    const int d0 = blockIdx.x * 64, b = blockIdx.y, ch = blockIdx.z;
    const int tid = threadIdx.x, wave = tid >> 6, lane = tid & 63;
    const int Lc = L_ / 4;
    const unsigned short* Ab = alpha + (size_t)b * T_ * L_ + ch * Lc;   // row stride L_
    const float*          Hb = H + ((size_t)b * L_ + ch * Lc) * DH + d0; // rows = l, stride DH

    const int lm = lane & 15, quad = lane >> 4;
    const int wm = wave >> 1, wn = wave & 1;
    f32x4 acc[4][2] = {};

    const int ar = lane >> 3, akb = (lane & 7) * 8;
    const int dg = tid & 7, lp = tid >> 3;     // B stage: 8d-group, l-pair index

    unsigned* B32 = (unsigned*)Bs;

    for (int k0 = 0; k0 < Lc; k0 += BK) {
        // A: async global->LDS (alpha rows, K=l contiguous)
        #pragma unroll
        for (int s = 0; s < 4; ++s) {
            const int rowb = s * 32 + wave * 8;
            const unsigned short* gp = Ab + (size_t)(rowb + ar) * L_ + k0 + akb;
            __builtin_amdgcn_global_load_lds(AS1(gp), AS3(&As[rowb * BK]), 16, 0, 0);
        }
        // B: H chunk 64 l x 64 d fp32 -> transposed bf16 LDS [d][l] (l-pairs packed in uint)
        {
            const float* r0 = Hb + (size_t)(k0 + 2 * lp) * DH + dg * 8;
            const float4 v0a = *(const float4*)(r0);
            const float4 v0b = *(const float4*)(r0 + 4);
            const float4 v1a = *(const float4*)(r0 + DH);
            const float4 v1b = *(const float4*)(r0 + DH + 4);
            float a0[8] = {v0a.x, v0a.y, v0a.z, v0a.w, v0b.x, v0b.y, v0b.z, v0b.w};
            float a1[8] = {v1a.x, v1a.y, v1a.z, v1a.w, v1b.x, v1b.y, v1b.z, v1b.w};
            #pragma unroll
            for (int i = 0; i < 8; ++i) {
                const int d = dg * 8 + i;
                B32[d * 33 + lp] = (unsigned)f2bf(a0[i]) | ((unsigned)f2bf(a1[i]) << 16);
            }
        }
        __syncthreads();
        #pragma unroll
        for (int ks = 0; ks < 2; ++ks) {
            bf16x8 a[4], bf[2];
            #pragma unroll
            for (int i = 0; i < 4; ++i)
                a[i] = *(const bf16x8*)(&As[(wm * 64 + i * 16 + lm) * BK + ks * 32 + quad * 8]);
            #pragma unroll
            for (int j = 0; j < 2; ++j) {
                const int d = wn * 32 + j * 16 + lm;
                const unsigned* p = B32 + d * 33 + ks * 16 + quad * 4;
                union { bf16x8 v; unsigned u[4]; } f;
                f.u[0] = p[0]; f.u[1] = p[1]; f.u[2] = p[2]; f.u[3] = p[3];
                bf[j] = f.v;
            }
            #pragma unroll
            for (int i = 0; i < 4; ++i)
                #pragma unroll
                for (int j = 0; j < 2; ++j)
                    acc[i][j] = __builtin_amdgcn_mfma_f32_16x16x32_bf16(a[i], bf[j], acc[i][j], 0, 0, 0);
        }
        __syncthreads();
    }
    float* Cb = partials + (((size_t)ch * B_ + b) * T_) * DH + d0;
    #pragma unroll
    for (int i = 0; i < 4; ++i)
        #pragma unroll
        for (int j = 0; j < 2; ++j)
            #pragma unroll
            for (int r = 0; r < 4; ++r)
                Cb[(size_t)(wm * 64 + i * 16 + quad * 4 + r) * DH + wn * 32 + j * 16 + lm] = acc[i][j][r];
}

// ---------------- Kernel 5: Z = sum of 4 partial chunks
__global__ __launch_bounds__(256) void reduce_kernel(const float* __restrict__ p,
                                                     float* __restrict__ Z) {
    const size_t n = (size_t)B_ * T_ * DH;
    const size_t i = ((size_t)blockIdx.x * 256 + threadIdx.x) * 4;
    const float4 a = *(const float4*)(p + i);
    const float4 b = *(const float4*)(p + n + i);
    const float4 c = *(const float4*)(p + 2 * n + i);
    const float4 d = *(const float4*)(p + 3 * n + i);
    float4 o;
    o.x = a.x + b.x + c.x + d.x;
    o.y = a.y + b.y + c.y + d.y;
    o.z = a.z + b.z + c.z + d.z;
    o.w = a.w + b.w + c.w + d.w;
    *(float4*)(Z + i) = o;
}

extern "C" void kernel_launch(void* const* d_in, const int* in_sizes, int n_in,
                              void* d_out, int out_size, void* d_ws, size_t ws_size,
                              hipStream_t stream) {
    const float* H    = (const float*)d_in[0];
    const float* G    = (const float*)d_in[1];
    const int*   mask = (const int*)d_in[2];
    const float* Wk   = (const float*)d_in[3];
    const float* Wq   = (const float*)d_in[4];
    float* Z = (float*)d_out;

    char* ws = (char*)d_ws;
    unsigned short* Qk     = (unsigned short*)ws;                       //  2 MB
    float*          logits = (float*)(ws + ((size_t)2  << 20));         // 16 MB
    unsigned short* alpha  = (unsigned short*)(ws + ((size_t)18 << 20)); //  8 MB
    float*          parts  = (float*)(ws + ((size_t)26 << 20));         // 16 MB

    qk_kernel<<<B_ * T_, 256, 0, stream>>>(G, Wq, Wk, Qk);
    logits_kernel<<<dim3(L_ / 64, B_), 256, 0, stream>>>(Qk, H, logits);
    softmax_kernel<<<B_ * T_, 256, 0, stream>>>(logits, mask, alpha);
    z_kernel<<<dim3(DH / 64, B_, 4), 256, 0, stream>>>(alpha, H, parts);
    reduce_kernel<<<(B_ * T_ * DH / 4) / 256, 256, 0, stream>>>(parts, Z);
}

// Round 3
// 285.351 us; speedup vs baseline: 2.1670x; 1.1829x over previous
//
#include <hip/hip_runtime.h>
#include <hip/hip_bf16.h>
#include <math.h>

#define B_  8
#define L_  4096
#define T_  128
#define DH  1024
#define DG  256
#define DP  256
#define BK  64

typedef short bf16x8 __attribute__((ext_vector_type(8)));
typedef float f32x4  __attribute__((ext_vector_type(4)));

#define AS1(p) ((const __attribute__((address_space(1))) void*)(p))
#define AS3(p) ((__attribute__((address_space(3))) void*)(p))

__device__ __forceinline__ unsigned short f2bf(float f) {
    unsigned u = __float_as_uint(f);
    unsigned r = (u + 0x7FFFu + ((u >> 16) & 1u)) >> 16;  // RNE
    return (unsigned short)r;
}

// ---------------- Kernel W: Wct[d,g] = (1/16) * sum_p Wk[d,p] * Wq[g,p]   (bf16 out)
// M=1024(d) x N=256(g) x K=256(p); tile 128x64; grid (4, 8) = 32 blocks
__global__ __launch_bounds__(256) void wct_kernel(const float* __restrict__ Wk,
                                                  const float* __restrict__ Wq,
                                                  unsigned short* __restrict__ Wct) {
    __shared__ __attribute__((aligned(16))) unsigned short As[128 * BK];
    __shared__ __attribute__((aligned(16))) unsigned short Bs[64 * BK];
    const int n0 = blockIdx.x * 64, m0 = blockIdx.y * 128;
    const int tid = threadIdx.x, wave = tid >> 6, lane = tid & 63;
    const int lm = lane & 15, quad = lane >> 4;
    const int wm = wave >> 1, wn = wave & 1;
    const int bc = (tid & 15) * 4, br = tid >> 4;
    f32x4 acc[4][2] = {};

    for (int k0 = 0; k0 < DP; k0 += BK) {
        #pragma unroll
        for (int s = 0; s < 8; ++s) {   // A: Wk rows m0..m0+127
            const int row = br + s * 16;
            const float4 v = *(const float4*)(Wk + (size_t)(m0 + row) * DP + k0 + bc);
            ushort4 p; p.x = f2bf(v.x); p.y = f2bf(v.y); p.z = f2bf(v.z); p.w = f2bf(v.w);
            *(ushort4*)(&As[row * BK + bc]) = p;
        }
        #pragma unroll
        for (int s = 0; s < 4; ++s) {   // B: Wq rows n0..n0+63
            const int row = br + s * 16;
            const float4 v = *(const float4*)(Wq + (size_t)(n0 + row) * DP + k0 + bc);
            ushort4 p; p.x = f2bf(v.x); p.y = f2bf(v.y); p.z = f2bf(v.z); p.w = f2bf(v.w);
            *(ushort4*)(&Bs[row * BK + bc]) = p;
        }
        __syncthreads();
        #pragma unroll
        for (int ks = 0; ks < 2; ++ks) {
            bf16x8 a[4], bf[2];
            #pragma unroll
            for (int i = 0; i < 4; ++i)
                a[i] = *(const bf16x8*)(&As[(wm * 64 + i * 16 + lm) * BK + ks * 32 + quad * 8]);
            #pragma unroll
            for (int j = 0; j < 2; ++j)
                bf[j] = *(const bf16x8*)(&Bs[(wn * 32 + j * 16 + lm) * BK + ks * 32 + quad * 8]);
            #pragma unroll
            for (int i = 0; i < 4; ++i)
                #pragma unroll
                for (int j = 0; j < 2; ++j)
                    acc[i][j] = __builtin_amdgcn_mfma_f32_16x16x32_bf16(a[i], bf[j], acc[i][j], 0, 0, 0);
        }
        __syncthreads();
    }
    unsigned short* Cb = Wct + (size_t)m0 * DG + n0;
    #pragma unroll
    for (int i = 0; i < 4; ++i)
        #pragma unroll
        for (int j = 0; j < 2; ++j)
            #pragma unroll
            for (int r = 0; r < 4; ++r)
                Cb[(size_t)(wm * 64 + i * 16 + quad * 4 + r) * DG + wn * 32 + j * 16 + lm] =
                    f2bf(acc[i][j][r] * 0.0625f);
}

// ---------------- Kernel Q: Qk[bt,d] = sum_g G[bt,g] * Wct[d,g]   (bf16 out)
// M=1024(bt) x N=1024(d) x K=256(g); tile 128x64; grid (16, 8) = 128 blocks
__global__ __launch_bounds__(256) void qproj_kernel(const float* __restrict__ G,
                                                    const unsigned short* __restrict__ Wct,
                                                    unsigned short* __restrict__ Qk) {
    __shared__ __attribute__((aligned(16))) unsigned short As[128 * BK];
    __shared__ __attribute__((aligned(16))) unsigned short Bs[64 * BK];
    const int n0 = blockIdx.x * 64, m0 = blockIdx.y * 128;
    const int tid = threadIdx.x, wave = tid >> 6, lane = tid & 63;
    const int lm = lane & 15, quad = lane >> 4;
    const int wm = wave >> 1, wn = wave & 1;
    const int bc = (tid & 15) * 4, br = tid >> 4;
    const int ar = lane >> 3, akb = (lane & 7) * 8;
    f32x4 acc[4][2] = {};

    for (int k0 = 0; k0 < DG; k0 += BK) {
        #pragma unroll
        for (int s = 0; s < 8; ++s) {   // A: G rows (fp32 -> bf16)
            const int row = br + s * 16;
            const float4 v = *(const float4*)(G + (size_t)(m0 + row) * DG + k0 + bc);
            ushort4 p; p.x = f2bf(v.x); p.y = f2bf(v.y); p.z = f2bf(v.z); p.w = f2bf(v.w);
            *(ushort4*)(&As[row * BK + bc]) = p;
        }
        #pragma unroll
        for (int s = 0; s < 2; ++s) {   // B: Wct rows (bf16, async direct to LDS)
            const int rowb = s * 32 + wave * 8;
            const unsigned short* gp = Wct + (size_t)(n0 + rowb + ar) * DG + k0 + akb;
            __builtin_amdgcn_global_load_lds(AS1(gp), AS3(&Bs[rowb * BK]), 16, 0, 0);
        }
        __syncthreads();
        #pragma unroll
        for (int ks = 0; ks < 2; ++ks) {
            bf16x8 a[4], bf[2];
            #pragma unroll
            for (int i = 0; i < 4; ++i)
                a[i] = *(const bf16x8*)(&As[(wm * 64 + i * 16 + lm) * BK + ks * 32 + quad * 8]);
            #pragma unroll
            for (int j = 0; j < 2; ++j)
                bf[j] = *(const bf16x8*)(&Bs[(wn * 32 + j * 16 + lm) * BK + ks * 32 + quad * 8]);
            #pragma unroll
            for (int i = 0; i < 4; ++i)
                #pragma unroll
                for (int j = 0; j < 2; ++j)
                    acc[i][j] = __builtin_amdgcn_mfma_f32_16x16x32_bf16(a[i], bf[j], acc[i][j], 0, 0, 0);
        }
        __syncthreads();
    }
    unsigned short* Cb = Qk + (size_t)m0 * DH + n0;
    #pragma unroll
    for (int i = 0; i < 4; ++i)
        #pragma unroll
        for (int j = 0; j < 2; ++j)
            #pragma unroll
            for (int r = 0; r < 4; ++r)
                Cb[(size_t)(wm * 64 + i * 16 + quad * 4 + r) * DH + wn * 32 + j * 16 + lm] =
                    f2bf(acc[i][j][r]);
}

// ---------------- Kernel 2: logits = Qk(bf16) . H^T(fp32->bf16)   tile 128t x 64l
__global__ __launch_bounds__(256) void logits_kernel(const unsigned short* __restrict__ Qk,
                                                     const float* __restrict__ H,
                                                     float* __restrict__ logits) {
    __shared__ __attribute__((aligned(16))) unsigned short As[T_ * BK];
    __shared__ __attribute__((aligned(16))) unsigned short Bs[64 * BK];
    const int b = blockIdx.y, l0 = blockIdx.x * 64;
    const int tid = threadIdx.x, wave = tid >> 6, lane = tid & 63;
    const unsigned short* Ab = Qk + (size_t)b * T_ * DH;
    const float*          Hb = H + ((size_t)b * L_ + l0) * DH;

    const int lm = lane & 15, quad = lane >> 4;
    const int wm = wave >> 1, wn = wave & 1;
    f32x4 acc[4][2] = {};
    const int ar = lane >> 3, akb = (lane & 7) * 8;
    const int bc = (tid & 15) * 4, br0 = tid >> 4;

    for (int k0 = 0; k0 < DH; k0 += BK) {
        #pragma unroll
        for (int s = 0; s < 4; ++s) {
            const int rowb = s * 32 + wave * 8;
            const unsigned short* gp = Ab + (size_t)(rowb + ar) * DH + k0 + akb;
            __builtin_amdgcn_global_load_lds(AS1(gp), AS3(&As[rowb * BK]), 16, 0, 0);
        }
        #pragma unroll
        for (int s = 0; s < 4; ++s) {
            const int row = br0 + s * 16;
            const float4 v = *(const float4*)(Hb + (size_t)row * DH + k0 + bc);
            ushort4 p; p.x = f2bf(v.x); p.y = f2bf(v.y); p.z = f2bf(v.z); p.w = f2bf(v.w);
            *(ushort4*)(&Bs[row * BK + bc]) = p;
        }
        __syncthreads();
        #pragma unroll
        for (int ks = 0; ks < 2; ++ks) {
            bf16x8 a[4], bf[2];
            #pragma unroll
            for (int i = 0; i < 4; ++i)
                a[i] = *(const bf16x8*)(&As[(wm * 64 + i * 16 + lm) * BK + ks * 32 + quad * 8]);
            #pragma unroll
            for (int j = 0; j < 2; ++j)
                bf[j] = *(const bf16x8*)(&Bs[(wn * 32 + j * 16 + lm) * BK + ks * 32 + quad * 8]);
            #pragma unroll
            for (int i = 0; i < 4; ++i)
                #pragma unroll
                for (int j = 0; j < 2; ++j)
                    acc[i][j] = __builtin_amdgcn_mfma_f32_16x16x32_bf16(a[i], bf[j], acc[i][j], 0, 0, 0);
        }
        __syncthreads();
    }
    float* Cb = logits + (size_t)b * T_ * L_ + l0;
    #pragma unroll
    for (int i = 0; i < 4; ++i)
        #pragma unroll
        for (int j = 0; j < 2; ++j)
            #pragma unroll
            for (int r = 0; r < 4; ++r)
                Cb[(size_t)(wm * 64 + i * 16 + quad * 4 + r) * L_ + wn * 32 + j * 16 + lm] = acc[i][j][r];
}

// ---------------- Kernel 3: masked softmax over L, fp32 in -> bf16 alpha out (vectorized)
__global__ __launch_bounds__(256) void softmax_kernel(const float* __restrict__ logits,
                                                      const int* __restrict__ mask,
                                                      unsigned short* __restrict__ alpha) {
    const int row = blockIdx.x;       // b*T + t
    const int b   = row >> 7;
    const int tid = threadIdx.x;
    const float4* p4 = (const float4*)(logits + (size_t)row * L_);
    const int4*   m4 = (const int4*)(mask + (size_t)b * L_);

    float vals[4][4];
    float vmax = -3.0e38f;
    #pragma unroll
    for (int s = 0; s < 4; ++s) {
        const int idx = tid + s * 256;
        float4 v = p4[idx];
        const int4 mm = m4[idx];
        v.x = mm.x ? -3.0e38f : v.x;
        v.y = mm.y ? -3.0e38f : v.y;
        v.z = mm.z ? -3.0e38f : v.z;
        v.w = mm.w ? -3.0e38f : v.w;
        vals[s][0] = v.x; vals[s][1] = v.y; vals[s][2] = v.z; vals[s][3] = v.w;
        vmax = fmaxf(vmax, fmaxf(fmaxf(v.x, v.y), fmaxf(v.z, v.w)));
    }
    #pragma unroll
    for (int off = 32; off; off >>= 1) vmax = fmaxf(vmax, __shfl_down(vmax, off, 64));

    __shared__ float red[4];
    __shared__ float bcast;
    const int wid = tid >> 6, lane = tid & 63;
    if (lane == 0) red[wid] = vmax;
    __syncthreads();
    if (tid == 0) bcast = fmaxf(fmaxf(red[0], red[1]), fmaxf(red[2], red[3]));
    __syncthreads();
    const float m = bcast;

    float sum = 0.f;
    #pragma unroll
    for (int s = 0; s < 4; ++s)
        #pragma unroll
        for (int i = 0; i < 4; ++i) {
            vals[s][i] = __expf(vals[s][i] - m);
            sum += vals[s][i];
        }
    #pragma unroll
    for (int off = 32; off; off >>= 1) sum += __shfl_down(sum, off, 64);
    __syncthreads();
    if (lane == 0) red[wid] = sum;
    __syncthreads();
    if (tid == 0) bcast = red[0] + red[1] + red[2] + red[3];
    __syncthreads();
    const float inv = 1.0f / bcast;

    unsigned short* arow = alpha + (size_t)row * L_;
    #pragma unroll
    for (int s = 0; s < 4; ++s) {
        ushort4 p;
        p.x = f2bf(vals[s][0] * inv); p.y = f2bf(vals[s][1] * inv);
        p.z = f2bf(vals[s][2] * inv); p.w = f2bf(vals[s][3] * inv);
        *(ushort4*)(arow + (size_t)(tid + s * 256) * 4) = p;
    }
}

// ---------------- Kernel 4: Z += alpha(bf16) . H(fp32->bf16, LDS-transposed), atomic epilogue
// tile 128t x 64d, K = L/4 per chunk; grid (16 d-tiles, 8 b, 4 chunks)
__global__ __launch_bounds__(256) void z_kernel(const unsigned short* __restrict__ alpha,
                                                const float* __restrict__ H,
                                                float* __restrict__ Z) {
    __shared__ __attribute__((aligned(16))) unsigned short As[T_ * BK];
    __shared__ __attribute__((aligned(16))) unsigned short Bs[64 * (BK + 2)];
    const int d0 = blockIdx.x * 64, b = blockIdx.y, ch = blockIdx.z;
    const int tid = threadIdx.x, wave = tid >> 6, lane = tid & 63;
    const int Lc = L_ / 4;
    const unsigned short* Ab = alpha + (size_t)b * T_ * L_ + ch * Lc;
    const float*          Hb = H + ((size_t)b * L_ + ch * Lc) * DH + d0;

    const int lm = lane & 15, quad = lane >> 4;
    const int wm = wave >> 1, wn = wave & 1;
    f32x4 acc[4][2] = {};
    const int ar = lane >> 3, akb = (lane & 7) * 8;
    const int dg = tid & 7, lp = tid >> 3;
    unsigned* B32 = (unsigned*)Bs;

    for (int k0 = 0; k0 < Lc; k0 += BK) {
        #pragma unroll
        for (int s = 0; s < 4; ++s) {
            const int rowb = s * 32 + wave * 8;
            const unsigned short* gp = Ab + (size_t)(rowb + ar) * L_ + k0 + akb;
            __builtin_amdgcn_global_load_lds(AS1(gp), AS3(&As[rowb * BK]), 16, 0, 0);
        }
        {
            const float* r0 = Hb + (size_t)(k0 + 2 * lp) * DH + dg * 8;
            const float4 v0a = *(const float4*)(r0);
            const float4 v0b = *(const float4*)(r0 + 4);
            const float4 v1a = *(const float4*)(r0 + DH);
            const float4 v1b = *(const float4*)(r0 + DH + 4);
            float a0[8] = {v0a.x, v0a.y, v0a.z, v0a.w, v0b.x, v0b.y, v0b.z, v0b.w};
            float a1[8] = {v1a.x, v1a.y, v1a.z, v1a.w, v1b.x, v1b.y, v1b.z, v1b.w};
            #pragma unroll
            for (int i = 0; i < 8; ++i) {
                const int d = dg * 8 + i;
                B32[d * 33 + lp] = (unsigned)f2bf(a0[i]) | ((unsigned)f2bf(a1[i]) << 16);
            }
        }
        __syncthreads();
        #pragma unroll
        for (int ks = 0; ks < 2; ++ks) {
            bf16x8 a[4], bf[2];
            #pragma unroll
            for (int i = 0; i < 4; ++i)
                a[i] = *(const bf16x8*)(&As[(wm * 64 + i * 16 + lm) * BK + ks * 32 + quad * 8]);
            #pragma unroll
            for (int j = 0; j < 2; ++j) {
                const int d = wn * 32 + j * 16 + lm;
                const unsigned* p = B32 + d * 33 + ks * 16 + quad * 4;
                union { bf16x8 v; unsigned u[4]; } f;
                f.u[0] = p[0]; f.u[1] = p[1]; f.u[2] = p[2]; f.u[3] = p[3];
                bf[j] = f.v;
            }
            #pragma unroll
            for (int i = 0; i < 4; ++i)
                #pragma unroll
                for (int j = 0; j < 2; ++j)
                    acc[i][j] = __builtin_amdgcn_mfma_f32_16x16x32_bf16(a[i], bf[j], acc[i][j], 0, 0, 0);
        }
        __syncthreads();
    }
    float* Cb = Z + (size_t)b * T_ * DH + d0;
    #pragma unroll
    for (int i = 0; i < 4; ++i)
        #pragma unroll
        for (int j = 0; j < 2; ++j)
            #pragma unroll
            for (int r = 0; r < 4; ++r)
                atomicAdd(&Cb[(size_t)(wm * 64 + i * 16 + quad * 4 + r) * DH + wn * 32 + j * 16 + lm],
                          acc[i][j][r]);
}

extern "C" void kernel_launch(void* const* d_in, const int* in_sizes, int n_in,
                              void* d_out, int out_size, void* d_ws, size_t ws_size,
                              hipStream_t stream) {
    const float* H    = (const float*)d_in[0];
    const float* G    = (const float*)d_in[1];
    const int*   mask = (const int*)d_in[2];
    const float* Wk   = (const float*)d_in[3];
    const float* Wq   = (const float*)d_in[4];
    float* Z = (float*)d_out;

    char* ws = (char*)d_ws;
    unsigned short* Wct    = (unsigned short*)ws;                        // 512 KB
    unsigned short* Qk     = (unsigned short*)(ws + ((size_t)1 << 20));  //   2 MB
    float*          logits = (float*)(ws + ((size_t)4 << 20));           //  17 MB
    unsigned short* alpha  = (unsigned short*)(ws + ((size_t)24 << 20)); // 8.4 MB

    hipMemsetAsync(Z, 0, (size_t)out_size * sizeof(float), stream);
    wct_kernel<<<dim3(DG / 64, DH / 128), 256, 0, stream>>>(Wk, Wq, Wct);
    qproj_kernel<<<dim3(DH / 64, (B_ * T_) / 128), 256, 0, stream>>>(G, Wct, Qk);
    logits_kernel<<<dim3(L_ / 64, B_), 256, 0, stream>>>(Qk, H, logits);
    softmax_kernel<<<B_ * T_, 256, 0, stream>>>(logits, mask, alpha);
    z_kernel<<<dim3(DH / 64, B_, 4), 256, 0, stream>>>(alpha, H, Z);
}